// Round 1
// baseline (50.094 us; speedup 1.0000x reference)
//
#include <hip/hip_runtime.h>
#include <math.h>

#define N_NEURONS 100000
#define N_PERCEPTORS 1024
#define N_MOTORS 256
#define N_CONNECTIONS 32
#define N_ACTIONS 16
#define BATCH 64
#define N_OUT (N_NEURONS - N_PERCEPTORS)   // 98976

// Kernel 1: compute sigmoid outputs for ONLY the last N_MOTORS neurons.
// Block = motor neuron m (256 blocks), lane = batch b (64 threads).
// nm is stored m-major: nm[m * BATCH + b].
__global__ __launch_bounds__(64) void motor_neurons_kernel(
    const float* __restrict__ x,
    const int*   __restrict__ idx,
    const float* __restrict__ w_sparse,
    const float* __restrict__ b_sparse,
    float* __restrict__ nm) {
  const int m = blockIdx.x;      // 0..255
  const int b = threadIdx.x;     // 0..63
  const int o = N_OUT - N_MOTORS + m;

  __shared__ int   s_idx[N_CONNECTIONS];
  __shared__ float s_w[N_CONNECTIONS];
  if (b < N_CONNECTIONS) {
    const long base = (long)o * N_CONNECTIONS + b;
    s_idx[b] = idx[base];
    s_w[b]   = w_sparse[base];
  }
  __syncthreads();

  const float* xb = x + (long)b * N_NEURONS;
  float acc = 0.f;
#pragma unroll
  for (int c = 0; c < N_CONNECTIONS; ++c) {
    acc += xb[s_idx[c]] * s_w[c];
  }
  const float pre = acc + b_sparse[o];
  const float sig = 1.f / (1.f + __expf(-pre));
  nm[m * BATCH + b] = sig;
}

// Kernel 2: q[b][a] = b_motor[a] + sum_m nm[m][b] * w_motor[a][m]
// One block, 1024 threads: thread = b*16 + a.
__global__ __launch_bounds__(1024) void motor_out_kernel(
    const float* __restrict__ nm,
    const float* __restrict__ w_motor,
    const float* __restrict__ b_motor,
    float* __restrict__ q) {
  const int t = threadIdx.x;   // 0..1023
  const int b = t >> 4;        // 0..63
  const int a = t & 15;        // 0..15
  float acc = b_motor[a];
#pragma unroll 8
  for (int m = 0; m < N_MOTORS; ++m) {
    acc += nm[m * BATCH + b] * w_motor[a * N_MOTORS + m];
  }
  q[b * N_ACTIONS + a] = acc;
}

extern "C" void kernel_launch(void* const* d_in, const int* in_sizes, int n_in,
                              void* d_out, int out_size, void* d_ws, size_t ws_size,
                              hipStream_t stream) {
  const float* x        = (const float*)d_in[0];
  const int*   idx      = (const int*)  d_in[1];
  const float* w_sparse = (const float*)d_in[2];
  const float* b_sparse = (const float*)d_in[3];
  const float* w_motor  = (const float*)d_in[4];
  const float* b_motor  = (const float*)d_in[5];
  float* q  = (float*)d_out;
  float* nm = (float*)d_ws;   // 256*64 floats = 64 KB scratch

  motor_neurons_kernel<<<N_MOTORS, BATCH, 0, stream>>>(x, idx, w_sparse, b_sparse, nm);
  motor_out_kernel<<<1, BATCH * N_ACTIONS, 0, stream>>>(nm, w_motor, b_motor, q);
}

// Round 2
// 16.991 us; speedup vs baseline: 2.9483x; 2.9483x over previous
//
#include <hip/hip_runtime.h>
#include <math.h>

#define N_NEURONS 100000
#define N_PERCEPTORS 1024
#define N_MOTORS 256
#define N_CONNECTIONS 32
#define N_ACTIONS 16
#define BATCH 64
#define N_OUT (N_NEURONS - N_PERCEPTORS)   // 98976

// Kernel 1: sigmoid outputs for ONLY the last N_MOTORS neurons.
// Block = motor neuron m (256 blocks), 256 threads = 4 waves.
// thread t: b = t&63 (batch), cg = t>>6 (connection group of 8).
// nm stored b-major: nm[b * N_MOTORS + m] (so kernel 2 reads coalesced).
__global__ __launch_bounds__(256) void motor_neurons_kernel(
    const float* __restrict__ x,
    const int*   __restrict__ idx,
    const float* __restrict__ w_sparse,
    const float* __restrict__ b_sparse,
    float* __restrict__ nm) {
  const int m = blockIdx.x;       // 0..255
  const int o = N_OUT - N_MOTORS + m;
  const int t = threadIdx.x;
  const int b  = t & 63;          // batch
  const int cg = t >> 6;          // 0..3, owns connections cg*8 .. cg*8+7

  __shared__ int   s_idx[N_CONNECTIONS];
  __shared__ float s_w[N_CONNECTIONS];
  if (t < N_CONNECTIONS) {
    const long base = (long)o * N_CONNECTIONS + t;
    s_idx[t] = idx[base];
    s_w[t]   = w_sparse[base];
  }
  __syncthreads();

  const float* xb = x + (long)b * N_NEURONS;
  float acc = 0.f;
#pragma unroll
  for (int i = 0; i < 8; ++i) {
    const int c = cg * 8 + i;
    acc += xb[s_idx[c]] * s_w[c];
  }

  __shared__ float part[4][64];
  part[cg][b] = acc;
  __syncthreads();

  if (t < 64) {
    const float pre = part[0][b] + part[1][b] + part[2][b] + part[3][b]
                    + b_sparse[o];
    nm[b * N_MOTORS + m] = 1.f / (1.f + __expf(-pre));
  }
}

// Kernel 2: q[b][a] = b_motor[a] + sum_m nm[b][m] * w_motor[a][m]
// 64 blocks (one per batch row) x 256 threads.
// thread t: a = t&15, chunk = t>>4 owns m in [chunk*16, chunk*16+16).
__global__ __launch_bounds__(256) void motor_out_kernel(
    const float* __restrict__ nm,
    const float* __restrict__ w_motor,
    const float* __restrict__ b_motor,
    float* __restrict__ q) {
  const int b = blockIdx.x;    // 0..63
  const int t = threadIdx.x;   // 0..255
  const int a     = t & 15;
  const int chunk = t >> 4;

  __shared__ float s[N_MOTORS];
  s[t] = nm[b * N_MOTORS + t];   // fully coalesced 1KB load
  __syncthreads();

  float acc = 0.f;
#pragma unroll
  for (int i = 0; i < 16; ++i) {
    const int m = chunk * 16 + i;
    acc += s[m] * w_motor[a * N_MOTORS + m];
  }

  __shared__ float p[16][16];    // p[a][chunk]
  p[a][chunk] = acc;
  __syncthreads();

  if (t < N_ACTIONS) {
    float sum = b_motor[t];
#pragma unroll
    for (int ch = 0; ch < 16; ++ch) sum += p[t][ch];
    q[b * N_ACTIONS + t] = sum;
  }
}

extern "C" void kernel_launch(void* const* d_in, const int* in_sizes, int n_in,
                              void* d_out, int out_size, void* d_ws, size_t ws_size,
                              hipStream_t stream) {
  const float* x        = (const float*)d_in[0];
  const int*   idx      = (const int*)  d_in[1];
  const float* w_sparse = (const float*)d_in[2];
  const float* b_sparse = (const float*)d_in[3];
  const float* w_motor  = (const float*)d_in[4];
  const float* b_motor  = (const float*)d_in[5];
  float* q  = (float*)d_out;
  float* nm = (float*)d_ws;   // BATCH * N_MOTORS floats = 64 KB scratch

  motor_neurons_kernel<<<N_MOTORS, 256, 0, stream>>>(x, idx, w_sparse, b_sparse, nm);
  motor_out_kernel<<<BATCH, 256, 0, stream>>>(nm, w_motor, b_motor, q);
}

// Round 3
// 11.688 us; speedup vs baseline: 4.2860x; 1.4537x over previous
//
#include <hip/hip_runtime.h>
#include <math.h>

#define N_NEURONS 100000
#define N_PERCEPTORS 1024
#define N_MOTORS 256
#define N_CONNECTIONS 32
#define N_ACTIONS 16
#define BATCH 64
#define N_OUT (N_NEURONS - N_PERCEPTORS)   // 98976
#define O_BASE (N_OUT - N_MOTORS)          // 98720

// Fully fused: block = batch row b (64 blocks), 512 threads = 8 waves.
// Phase 1: thread t owns (neuron m = t>>1, half h = t&1): 16 gathers+FMA.
// Phase 2: combine halves + bias + sigmoid -> s_nm[256] in LDS.
// Phase 3: q[b][a] = b_motor[a] + sum_m s_nm[m]*w_motor[a][m] via 256 threads.
__global__ __launch_bounds__(512) void brain_fused_kernel(
    const float* __restrict__ x,
    const int*   __restrict__ idx,
    const float* __restrict__ w_sparse,
    const float* __restrict__ b_sparse,
    const float* __restrict__ w_motor,
    const float* __restrict__ b_motor,
    float* __restrict__ q) {
  const int b = blockIdx.x;      // 0..63
  const int t = threadIdx.x;     // 0..511
  const int m = t >> 1;          // 0..255 motor neuron
  const int h = t & 1;           // half: connections h*16 .. h*16+15
  const int o = O_BASE + m;

  // idx/w for this thread's 16 connections: contiguous 64 B, fully coalesced.
  const long base = (long)o * N_CONNECTIONS + h * 16;
  const int4*   ip = (const int4*)  (idx      + base);
  const float4* wp = (const float4*)(w_sparse + base);
  int4   i0 = ip[0], i1 = ip[1], i2 = ip[2], i3 = ip[3];
  float4 w0 = wp[0], w1 = wp[1], w2 = wp[2], w3 = wp[3];

  const float* xb = x + (long)b * N_NEURONS;
  float acc = 0.f;
  acc += xb[i0.x]*w0.x + xb[i0.y]*w0.y + xb[i0.z]*w0.z + xb[i0.w]*w0.w;
  acc += xb[i1.x]*w1.x + xb[i1.y]*w1.y + xb[i1.z]*w1.z + xb[i1.w]*w1.w;
  acc += xb[i2.x]*w2.x + xb[i2.y]*w2.y + xb[i2.z]*w2.z + xb[i2.w]*w2.w;
  acc += xb[i3.x]*w3.x + xb[i3.y]*w3.y + xb[i3.z]*w3.z + xb[i3.w]*w3.w;

  __shared__ float part[512];
  part[t] = acc;
  __syncthreads();

  __shared__ float s_nm[N_MOTORS];
  if (t < N_MOTORS) {
    const float pre = part[2*t] + part[2*t + 1] + b_sparse[O_BASE + t];
    s_nm[t] = 1.f / (1.f + __expf(-pre));
  }
  __syncthreads();

  // Phase 3: 256 threads, thread = (chunk = t>>4, a = t&15) covers m-range.
  __shared__ float p[N_MOTORS];   // p[chunk*16 + a]
  if (t < N_MOTORS) {
    const int a     = t & 15;
    const int chunk = t >> 4;
    const float* wm = w_motor + a * N_MOTORS + chunk * 16;
    const float* sm = s_nm + chunk * 16;
    float accq = 0.f;
#pragma unroll
    for (int i = 0; i < 16; ++i) accq += sm[i] * wm[i];
    p[t] = accq;
  }
  __syncthreads();

  if (t < N_ACTIONS) {
    float sum = b_motor[t];
#pragma unroll
    for (int ch = 0; ch < 16; ++ch) sum += p[ch * 16 + t];
    q[b * N_ACTIONS + t] = sum;
  }
}

extern "C" void kernel_launch(void* const* d_in, const int* in_sizes, int n_in,
                              void* d_out, int out_size, void* d_ws, size_t ws_size,
                              hipStream_t stream) {
  const float* x        = (const float*)d_in[0];
  const int*   idx      = (const int*)  d_in[1];
  const float* w_sparse = (const float*)d_in[2];
  const float* b_sparse = (const float*)d_in[3];
  const float* w_motor  = (const float*)d_in[4];
  const float* b_motor  = (const float*)d_in[5];
  float* q = (float*)d_out;

  brain_fused_kernel<<<BATCH, 512, 0, stream>>>(
      x, idx, w_sparse, b_sparse, w_motor, b_motor, q);
}